// Round 5
// baseline (610.193 us; speedup 1.0000x reference)
//
#include <hip/hip_runtime.h>
#include <stdint.h>

#define NB 1024
#define ND 512
#define NC 100000
#define MTILES 391       // ceil(NC/256)
#define NBLK 1568        // 49*32 grid, 4 with mt>=MTILES exit early
#define MARGINF 0.1f

using bf16x8 = __attribute__((ext_vector_type(8))) short;
using f32x4  = __attribute__((ext_vector_type(4))) float;

// ---------- helpers ----------
__device__ __forceinline__ uint32_t f2bf(float f) {
  uint32_t u = __float_as_uint(f);
  return (u + 0x7fffu + ((u >> 16) & 1u)) >> 16;
}
__device__ __forceinline__ uint32_t pack2bf(float x, float y) {
  return f2bf(x) | (f2bf(y) << 16);
}

// ---------- normalize fp32 rows -> bf16 in MFMA-FRAGMENT layout ----------
// 256 thr, 16 rows per tile. Frag-tile = 16KB; fragment kc (1KB) covers
// k in [kc*32,+32); 16B unit u = g*16+rs holds row rs, k = kc*32+g*8..+8 —
// the 16x16x32 MFMA operand order (lane fragment at base + lane*16).
__device__ __forceinline__ void normalize_body(const float* __restrict__ src,
                                               uint16_t* __restrict__ dst,
                                               int blk) {
  __shared__ uint16_t lds[16][520];      // 1040B row stride (bank skew)
  const int lane = threadIdx.x & 63;
  const int wv = threadIdx.x >> 6;
  const size_t R0 = (size_t)blk << 4;
  #pragma unroll
  for (int i = 0; i < 4; ++i) {
    const int r = (wv << 2) + i;         // local row 0..15
    const float4* s = (const float4*)(src + (R0 + r) * ND) + (lane << 1);
    float4 a = s[0], b = s[1];
    float ss = a.x*a.x + a.y*a.y + a.z*a.z + a.w*a.w
             + b.x*b.x + b.y*b.y + b.z*b.z + b.w*b.w;
    #pragma unroll
    for (int o = 32; o; o >>= 1) ss += __shfl_xor(ss, o);
    const float inv = 1.0f / fmaxf(sqrtf(ss), 1e-8f);
    uint4 o4;
    o4.x = pack2bf(a.x * inv, a.y * inv);
    o4.y = pack2bf(a.z * inv, a.w * inv);
    o4.z = pack2bf(b.x * inv, b.y * inv);
    o4.w = pack2bf(b.z * inv, b.w * inv);
    *(uint4*)(&lds[r][lane << 3]) = o4;  // row-major, byte off lane*16
  }
  __syncthreads();
  uint16_t* out = dst + ((size_t)blk << 13);
  #pragma unroll
  for (int c = 0; c < 4; ++c) {
    const int idx = (c << 8) + threadIdx.x;        // 16B-unit index 0..1023
    const int kc = idx >> 6, g = (idx >> 4) & 3, rs = idx & 15;
    uint4 v = *(const uint4*)(&lds[rs][(kc << 5) + (g << 3)]);
    ((uint4*)out)[idx] = v;
  }
}

__global__ __launch_bounds__(256)
void normalize_relayout(const float* __restrict__ src, uint16_t* __restrict__ dst) {
  normalize_body(src, dst, blockIdx.x);
}

// ---------- exact fp32 target cosine t_b ----------
__device__ __forceinline__ void tcos_body(const float* __restrict__ x,
                                          const float* __restrict__ cls,
                                          const int* __restrict__ tgt,
                                          float* __restrict__ t, int b) {
  const int row = tgt[b];
  const float2* xr = (const float2*)(x + (size_t)b * ND);
  const float2* cr = (const float2*)(cls + (size_t)row * ND);
  float2 xv = xr[threadIdx.x], cv = cr[threadIdx.x];
  float sx = xv.x * xv.x + xv.y * xv.y;
  float sc = cv.x * cv.x + cv.y * cv.y;
  float sd = xv.x * cv.x + xv.y * cv.y;
  #pragma unroll
  for (int o = 32; o; o >>= 1) {
    sx += __shfl_down(sx, o);
    sc += __shfl_down(sc, o);
    sd += __shfl_down(sd, o);
  }
  __shared__ float r[3][4];
  const int wv = threadIdx.x >> 6;
  if ((threadIdx.x & 63) == 0) { r[0][wv] = sx; r[1][wv] = sc; r[2][wv] = sd; }
  __syncthreads();
  if (threadIdx.x == 0) {
    float ax = r[0][0] + r[0][1] + r[0][2] + r[0][3];
    float ac = r[1][0] + r[1][1] + r[1][2] + r[1][3];
    float ad = r[2][0] + r[2][1] + r[2][2] + r[2][3];
    t[b] = ad / (fmaxf(sqrtf(ax), 1e-8f) * fmaxf(sqrtf(ac), 1e-8f));
  }
}

// ---------- kernel 1: fused prep (Xf normalize + target cos + zero) --------
// blocks 0..63: normalize inputs -> Xf; 64..1087: target cos; 1088: zero
// accum[0..63] (slot 63 doubles as the GEMM's done-counter).
__global__ __launch_bounds__(256)
void prep_kernel(const float* __restrict__ inputs, const float* __restrict__ cls,
                 const int* __restrict__ tgt, uint16_t* __restrict__ Xf,
                 float* __restrict__ t, float* __restrict__ accum) {
  const int bid = blockIdx.x;
  if (bid < 64) {
    normalize_body(inputs, Xf, bid);
  } else if (bid < 64 + NB) {
    tcos_body(inputs, cls, tgt, t, bid - 64);
  } else {
    if (threadIdx.x < 64) accum[threadIdx.x] = 0.0f;
  }
}

// ---------- kernel 3: MFMA GEMM, counted-lgkm software pipeline ----------
// 512 thr = 8 waves (2M x 4N). Block tile 256x256, wave 128x64 = 8x4 of
// 16x16x32. BK=32 -> 16 K-tiles; 4-deep LDS ring (4 x 32KB: A 16K + B 16K),
// staged 3 ahead via global_load_lds (waves 0-3 stage A, 4-7 stage B).
// KEY CHANGE vs r3: ds_reads run ONE PHASE AHEAD of their consuming MFMA
// with COUNTED lgkmcnt, so the LDS pipe drains concurrently with the MFMA
// pipe (r3's lgkmcnt(0)-after-barrier serialized them = the 2560cyc/tile
// plateau). Per tile:
//   LO: STAGE(kt+3); issue a47(kt) reads; lgkmcnt(4); MFMA_LO(a03,B)
//       -> a47 drains under MFMA_LO
//   HI: vmcnt(8); lgkmcnt(0); s_barrier (the ONE hazard barrier: publishes
//       STAGE(kt+1), and all reads of tile kt are provably done before it);
//       issue a03(kt+1)+B(kt+1) reads; MFMA_HI(a47,B)
//       -> next tile's 8 reads drain under MFMA_HI
// B is double-buffered (bA/bB, compile-time parity); A frags single-buffered
// (WAR-safe: overwriting ds_reads are issued after the consuming MFMAs, and
// ds returns land >=64cyc later).
__device__ __forceinline__ void gload16(const char* g, char* l) {
  __builtin_amdgcn_global_load_lds(
      (__attribute__((address_space(1))) void*)(g),
      (__attribute__((address_space(3))) void*)(l), 16, 0, 0);
}
#define WAITVM(N)  asm volatile("s_waitcnt vmcnt(" #N ")" ::: "memory")
#define LGKM(N)    asm volatile("s_waitcnt lgkmcnt(" #N ")" ::: "memory")
#define SBAR()     __builtin_amdgcn_sched_barrier(0)

__global__ __launch_bounds__(512, 2)
void hinge_gemm_pipe(const uint16_t* __restrict__ Wf,   // frag-layout classes
                     const uint16_t* __restrict__ Xf,   // frag-layout inputs
                     const float* __restrict__ t,       // [NB]
                     float* __restrict__ accum,         // [64]; [63]=counter
                     float* __restrict__ outp) {
  const int id = blockIdx.x;
  // bijective XCD swizzle: same-mt blocks share id%8 -> same XCD L2
  const int mt = (id & 7) + ((id >> 5) << 3);   // 0..391
  const int nt = (id >> 3) & 3;                 // 0..3
  unsigned* ctr = (unsigned*)(accum + 63);

  __shared__ __align__(1024) char lds[131072];  // 4 ring slots x 32KB
  __shared__ float part[8];
  __shared__ bool lastf;

  const int lane = threadIdx.x & 63;
  const int wv = threadIdx.x >> 6;
  const int wm = wv & 1;        // 128-row half of A
  const int wn = wv >> 1;       // 64-col quarter of B
  const int laneoff = lane << 4;
  const int aoff = wm << 13;                 // A region: wm*8 slices * 1KB
  const int boff = (1 << 14) + (wn << 12);   // B region + wn*4 slices

  // finalize-if-last helper (also run by the 4 early-exit blocks)
  auto epilogue_mark = [&]() {
    __threadfence();
    if (threadIdx.x == 0) lastf = (atomicAdd(ctr, 1u) == (unsigned)(NBLK - 1));
    __syncthreads();
    if (lastf) {
      float v = 0.f;
      if (threadIdx.x < 32) v = atomicAdd(&accum[threadIdx.x], 0.0f); // coherent read
      #pragma unroll
      for (int o = 32; o; o >>= 1) v += __shfl_down(v, o);
      if (threadIdx.x == 0) outp[0] = v * (1.0f / (float)NB) - MARGINF;
    }
  };

  if (mt >= MTILES) { epilogue_mark(); return; }

  // staging roles: waves 0-3 stage the A-tile (4 slices each), 4-7 the B-tile
  const char* gstage;
  int dstage;
  if (wv < 4) {
    gstage = (const char*)Wf + (((size_t)(mt * 16 + wv * 4)) << 14) + laneoff;
    dstage = (wv * 4) << 10;
  } else {
    gstage = (const char*)Xf + (((size_t)(nt * 16 + (wv - 4) * 4)) << 14) + laneoff;
    dstage = (1 << 14) + (((wv - 4) * 4) << 10);
  }

  f32x4 acc[8][4];
  #pragma unroll
  for (int i = 0; i < 8; ++i)
    #pragma unroll
    for (int j = 0; j < 4; ++j)
      acc[i][j] = (f32x4){0.f, 0.f, 0.f, 0.f};

  bf16x8 a03[4], a47[4], bA[4], bB[4];

#define STAGE(T) {                                                         \
    char* lb_ = lds + (((T) & 3) << 15) + dstage;                          \
    const char* g_ = gstage + ((size_t)(T) << 10);                         \
    gload16(g_,          lb_);                                             \
    gload16(g_ + 16384,  lb_ + 1024);                                      \
    gload16(g_ + 32768,  lb_ + 2048);                                      \
    gload16(g_ + 49152,  lb_ + 3072); }

#define ISSUE_A03(KT) {                                                    \
    const char* b_ = lds + (((KT) & 3) << 15) + aoff + laneoff;            \
    a03[0] = *(const bf16x8*)(b_);                                         \
    a03[1] = *(const bf16x8*)(b_ + 1024);                                  \
    a03[2] = *(const bf16x8*)(b_ + 2048);                                  \
    a03[3] = *(const bf16x8*)(b_ + 3072); }

#define ISSUE_A47(KT) {                                                    \
    const char* b_ = lds + (((KT) & 3) << 15) + aoff + laneoff;            \
    a47[0] = *(const bf16x8*)(b_ + 4096);                                  \
    a47[1] = *(const bf16x8*)(b_ + 5120);                                  \
    a47[2] = *(const bf16x8*)(b_ + 6144);                                  \
    a47[3] = *(const bf16x8*)(b_ + 7168); }

#define ISSUE_B(KT, BR) {                                                  \
    const char* b_ = lds + (((KT) & 3) << 15) + boff + laneoff;            \
    BR[0] = *(const bf16x8*)(b_);                                          \
    BR[1] = *(const bf16x8*)(b_ + 1024);                                   \
    BR[2] = *(const bf16x8*)(b_ + 2048);                                   \
    BR[3] = *(const bf16x8*)(b_ + 3072); }

#define MFMA_LO(BR) {                                                      \
    __builtin_amdgcn_s_setprio(1);                                         \
    _Pragma("unroll")                                                      \
    for (int m_ = 0; m_ < 4; ++m_)                                         \
      _Pragma("unroll")                                                    \
      for (int j_ = 0; j_ < 4; ++j_)                                       \
        acc[m_][j_] = __builtin_amdgcn_mfma_f32_16x16x32_bf16(             \
            a03[m_], BR[j_], acc[m_][j_], 0, 0, 0);                        \
    __builtin_amdgcn_s_setprio(0); }

#define MFMA_HI(BR) {                                                      \
    __builtin_amdgcn_s_setprio(1);                                         \
    _Pragma("unroll")                                                      \
    for (int m_ = 0; m_ < 4; ++m_)                                         \
      _Pragma("unroll")                                                    \
      for (int j_ = 0; j_ < 4; ++j_)                                       \
        acc[m_ + 4][j_] = __builtin_amdgcn_mfma_f32_16x16x32_bf16(         \
            a47[m_], BR[j_], acc[m_ + 4][j_], 0, 0, 0);                    \
    __builtin_amdgcn_s_setprio(0); }

// One K-tile. BP = this tile's B regs, BN = next tile's. Steady state at the
// WAITVM: 12 stage-loads outstanding -> vmcnt(8) means STAGE(KT+1) landed.
// lgkmcnt(4) in LO: a03/B(KT) done (8 reads from prev HI), a47 pending.
#define TILE(KT, BP, BN, DOSTAGE, VMW) {                                   \
    if (DOSTAGE) STAGE((KT) + 3);                                          \
    ISSUE_A47(KT);                                                         \
    SBAR();                                                                \
    LGKM(4);                                                               \
    SBAR();                                                                \
    MFMA_LO(BP);                                                           \
    VMW;                                                                   \
    LGKM(0);                                                               \
    SBAR();                                                                \
    __builtin_amdgcn_s_barrier();                                          \
    ISSUE_A03((KT) + 1);                                                   \
    ISSUE_B((KT) + 1, BN);                                                 \
    SBAR();                                                                \
    MFMA_HI(BP); }

#define TILE_LAST(KT, BP) {                                                \
    ISSUE_A47(KT);                                                         \
    SBAR();                                                                \
    LGKM(4);                                                               \
    SBAR();                                                                \
    MFMA_LO(BP);                                                           \
    LGKM(0);                                                               \
    SBAR();                                                                \
    MFMA_HI(BP); }

  // prologue: 3 tiles staged; publish tile 0; preload its frags
  STAGE(0); STAGE(1); STAGE(2);
  WAITVM(8);                         // tile 0's 12 loads landed (8 newer out)
  __builtin_amdgcn_s_barrier();
  ISSUE_A03(0);
  ISSUE_B(0, bA);
  SBAR();

  #pragma unroll 1
  for (int tt = 0; tt < 6; ++tt) {
    const int kt = tt << 1;
    TILE(kt,     bA, bB, 1, WAITVM(8));
    TILE(kt + 1, bB, bA, 1, WAITVM(8));
  }
  TILE(12, bA, bB, 1, WAITVM(8));    // stages A/B tile 15
  TILE(13, bB, bA, 0, WAITVM(4));    // drains STAGE(14)
  TILE(14, bA, bB, 0, WAITVM(0));    // drains STAGE(15)
  TILE_LAST(15, bB);

  // ---- epilogue: hinge + block reduction ----
  // C/D: col(N) = lane&15, row(M) = (lane>>4)*4 + reg
  const int m0 = mt << 8, n0 = nt << 8;
  const int lr = lane & 15;
  const int rb4 = (lane >> 4) << 2;
  float local = 0.f;
  #pragma unroll
  for (int j = 0; j < 4; ++j) {
    const int n = n0 + (wn << 6) + (j << 4) + lr;
    const float base = MARGINF - t[n];
    #pragma unroll
    for (int ms = 0; ms < 8; ++ms) {
      const int mr = m0 + (wm << 7) + (ms << 4) + rb4;
      f32x4 v = acc[ms][j];
      #pragma unroll
      for (int rr = 0; rr < 4; ++rr)
        if (mr + rr < NC) local += fmaxf(base + v[rr], 0.f);
    }
  }
  #pragma unroll
  for (int o = 32; o; o >>= 1) local += __shfl_down(local, o);
  if (lane == 0) part[wv] = local;
  __syncthreads();
  if (threadIdx.x == 0) {
    float s = 0.f;
    #pragma unroll
    for (int i = 0; i < 8; ++i) s += part[i];
    atomicAdd(&accum[id & 31], s);
  }
  epilogue_mark();
#undef STAGE
#undef ISSUE_A03
#undef ISSUE_A47
#undef ISSUE_B
#undef MFMA_LO
#undef MFMA_HI
#undef TILE
#undef TILE_LAST
}

// ---------- workspace layout ----------
//   Wf   : 0            .. 102,400,000   (6250 frag-tiles x 16KB)
//   Xf   : 102,400,000  .. 103,448,576   (64 frag-tiles x 16KB)
//   t    : 103,448,576  .. 103,452,672   (NB fp32)
//   acc  : 103,452,672  .. +256          (64 fp32; [0..31] sums, [63] ctr)
// NOTE: GEMM mt=390 reads frag-tiles 6250..6255 which overrun Wf into Xf —
// allocated, finite bf16 garbage, masked by mr<NC in the epilogue.
#define WS_WF 0
#define WS_XF 102400000ull
#define WS_T  103448576ull
#define WS_ACC 103452672ull

extern "C" void kernel_launch(void* const* d_in, const int* in_sizes, int n_in,
                              void* d_out, int out_size, void* d_ws, size_t ws_size,
                              hipStream_t stream) {
  const float* inputs = (const float*)d_in[0];
  const float* cls    = (const float*)d_in[1];
  const int*   tgt    = (const int*)d_in[2];
  float* out = (float*)d_out;
  char* ws = (char*)d_ws;
  uint16_t* Wf = (uint16_t*)(ws + WS_WF);
  uint16_t* Xf = (uint16_t*)(ws + WS_XF);
  float* t     = (float*)(ws + WS_T);
  float* accum = (float*)(ws + WS_ACC);

  // 3 dispatches total (was 6): prep fuses Xf-normalize + target-cos + zero;
  // finalize is fused into the GEMM via a device-scope done-counter.
  prep_kernel<<<64 + NB + 1, 256, 0, stream>>>(inputs, cls, tgt, Xf, t, accum);
  normalize_relayout<<<6250, 256, 0, stream>>>(cls, Wf);
  hinge_gemm_pipe<<<NBLK, 512, 0, stream>>>(Wf, Xf, t, accum, out);
}